// Round 7
// baseline (3613.784 us; speedup 1.0000x reference)
//
#include <hip/hip_runtime.h>
#include <hip/hip_bf16.h>

// GRU last-hidden: B=64, T=512, I=256, H=512, fp32 in/out.
// Persistent kernel: 64 WGs x 256 thr. WG w owns h-cols [8w,8w+8) for ALL
// batches; weights live in VGPR MFMA B-fragments for the whole kernel.
//
// Round-7: R5 protocol + NO producer ack + epoch-validated blocks, small ws.
//  - h block per (wg,b) = 32 B: [stamp,u32 pair01, stamp, pair23 | stamp,
//    pair45, stamp, pair67]; stamp = t+2 (u32), pair = 2 packed bf16.
//  - producer: LDS transpose -> 2 coalesced dwordx4 sc1 stores per lane<16,
//    fire-and-forget; tag[wave][wg]=t+2 stored immediately (NO vmcnt ack).
//  - consumer: cheap 1-dword tag poll (R5 pattern) -> 32-load sc1 burst ->
//    validate stamps -> rare re-burst (tag can outrun data in fabric).
//  - deadlock-free: data stores always drain; validation-retry terminates.
//    Overwrite safety: producer validates epoch t+2 from ALL WGs before
//    overwriting b_{t&1}, proving every step-t reader consumed its data.
//  - ws = 8K slots + 1K tags + 2x128K h bufs ~= 272 KB (no x staging; x is
//    read fp32 cached and truncation-packed to bf16 with v_perm on the fly).

#define NB 64
#define NT 512
#define NI 256
#define NH 512

typedef __attribute__((ext_vector_type(8))) short bf16x8;
typedef __attribute__((ext_vector_type(4))) float f32x4;
typedef __attribute__((ext_vector_type(4))) int i32x4;

static __device__ __forceinline__ short f2b(float f) {
  // fp32 -> bf16 bits, round-to-nearest-even (finite inputs)
  unsigned u = __builtin_bit_cast(unsigned, f);
  unsigned r = (u + 0x7fffu + ((u >> 16) & 1u)) >> 16;
  return (short)r;
}
static __device__ __forceinline__ float sigm(float x) {
  return 1.0f / (1.0f + __expf(-x));
}
static __device__ __forceinline__ float tanh_f(float x) {
  return 1.0f - 2.0f / (__expf(2.0f * x) + 1.0f);
}

__global__ __launch_bounds__(256, 1)
void gru_persistent(const float* __restrict__ x,
                    const float* __restrict__ Wih,
                    const float* __restrict__ Whh,
                    const float* __restrict__ bih,
                    const float* __restrict__ bhh,
                    float* __restrict__ out,
                    unsigned char* __restrict__ ws) {
  const int wg   = blockIdx.x;    // 0..63 : owns h-cols [8wg, 8wg+8)
  const int tid  = threadIdx.x;   // 0..255
  const int wave = tid >> 6;      // 0..3  : owns batches [16*wave, 16*wave+16)
  const int lane = tid & 63;
  const int c    = lane & 15;     // tile col / A-row index
  const int q    = lane >> 4;     // quad: k-group (A/B), row-group (C/D)

  // ws: [0,8K) init slots; [8K,9K) tags[4][64]; hb0 at 16K, hb1 at 16K+128K.
  // Each h buf: [64 wg][64 b][8 u32] = 128 KB. Total ~272 KB.
  int* slots = (int*)ws;
  int* tags  = (int*)(ws + 8192);
  unsigned* hb0 = (unsigned*)(ws + 16384);
  unsigned* hb1 = (unsigned*)(ws + 16384 + 131072);

  __shared__ unsigned trans[4][16][8];  // per-wave 32B-row transpose bounce

  // ---- prologue: zero h0 (stamps 0 + data 0) and tags ----
  hb0[wg * 256 + tid] = 0u;
  hb0[16384 + wg * 256 + tid] = 0u;   // 32768 u32 total over 16384 threads
  if (wg == 0) tags[tid] = 0;         // 256 tags
  // hb1 left poisoned: 0xAAAAAAAA never equals a valid stamp.

  // ---- loop-invariant weight fragments into registers (RNE) ----
  bf16x8 wh[2][16];  // W_hh, K=512 -> 16 k-steps
  bf16x8 wi[2][8];   // W_ih, K=256 -> 8 k-steps
#pragma unroll
  for (int nt = 0; nt < 2; nt++) {
    int nl = nt * 16 + c;
    bool valid = nl < 24;
    int gate = nl >> 3;
    int jj = nl & 7;
    int grow = valid ? (gate * NH + wg * 8 + jj) : 0;
#pragma unroll
    for (int kk = 0; kk < 16; kk++) {
      const float* p = Whh + (size_t)grow * NH + kk * 32 + q * 8;
      bf16x8 f;
#pragma unroll
      for (int e = 0; e < 8; e++) f[e] = valid ? f2b(p[e]) : (short)0;
      wh[nt][kk] = f;
    }
#pragma unroll
    for (int kk = 0; kk < 8; kk++) {
      const float* p = Wih + (size_t)grow * NI + kk * 32 + q * 8;
      bf16x8 f;
#pragma unroll
      for (int e = 0; e < 8; e++) f[e] = valid ? f2b(p[e]) : (short)0;
      wi[nt][kk] = f;
    }
  }

  const int jcol = wg * 8 + (c & 7);
  const float bri = bih[jcol],          brh = bhh[jcol];
  const float bzi = bih[NH + jcol],     bzh = bhh[NH + jcol];
  const float bni = bih[2 * NH + jcol], bnh = bhh[2 * NH + jcol];

  float hold[4] = {0.f, 0.f, 0.f, 0.f};  // fp32 master state (c<8 lanes)

  // ---- one-time init barrier: hb0 + tag zeros visible device-wide ----
  __syncthreads();
  if (tid == 0)
    __hip_atomic_store(&slots[wg * 32], 1, __ATOMIC_RELEASE,
                       __HIP_MEMORY_SCOPE_AGENT);
  if (wave == 0) {
    while (__hip_atomic_load(&slots[lane * 32], __ATOMIC_RELAXED,
                             __HIP_MEMORY_SCOPE_AGENT) < 1)
      __builtin_amdgcn_s_sleep(1);
  }
  __syncthreads();
  __threadfence();

  const int b0 = wave * 16 + c;       // A-fragment batch row for this lane
  int* mytags = tags + wave * 64;     // this wave-group's 64 tags
  const int* tagp = mytags + lane;    // per-lane poll address (coalesced)

  for (int t = 0; t < NT; t++) {
    const unsigned* hcur = (t & 1) ? hb1 : hb0;
    unsigned* hnext      = (t & 1) ? hb0 : hb1;

    f32x4 aX0 = {0.f, 0.f, 0.f, 0.f}, aX1 = {0.f, 0.f, 0.f, 0.f};
    f32x4 aH0 = {0.f, 0.f, 0.f, 0.f}, aH1 = {0.f, 0.f, 0.f, 0.f};

    // x-projection: fp32 cached loads, truncation-pack to bf16 via v_perm
    // (bytes [3:2] of each float = truncated bf16). Fully before the poll.
    const int* xrow = (const int*)(x + ((size_t)b0 * NT + t) * NI);
#pragma unroll
    for (int kk = 0; kk < 8; kk++) {
      const i32x4* xp = (const i32x4*)(xrow + kk * 32 + q * 8);
      i32x4 u0 = xp[0], u1 = xp[1];
      i32x4 pk;
      pk[0] = (int)__builtin_amdgcn_perm((unsigned)u0[1], (unsigned)u0[0],
                                         0x07060302u);
      pk[1] = (int)__builtin_amdgcn_perm((unsigned)u0[3], (unsigned)u0[2],
                                         0x07060302u);
      pk[2] = (int)__builtin_amdgcn_perm((unsigned)u1[1], (unsigned)u1[0],
                                         0x07060302u);
      pk[3] = (int)__builtin_amdgcn_perm((unsigned)u1[3], (unsigned)u1[2],
                                         0x07060302u);
      bf16x8 a = __builtin_bit_cast(bf16x8, pk);
      aX0 = __builtin_amdgcn_mfma_f32_16x16x32_bf16(a, wi[0][kk], aX0, 0, 0, 0);
      aX1 = __builtin_amdgcn_mfma_f32_16x16x32_bf16(a, wi[1][kk], aX1, 0, 0, 0);
    }

    // cheap tag poll: 1 coalesced sc1 dword per wave per iteration
    if (t > 0) {
      const int need = t + 1;
      while (true) {
        int v;
        asm volatile("global_load_dword %0, %1, off sc1"
                     : "=v"(v) : "v"(tagp));
        asm volatile("s_waitcnt vmcnt(0)" : "+v"(v)::"memory");
        if (__all(v >= need)) break;
      }
    }

    // h burst: 32 coalesced sc1 dwordx4 loads (A halves then B halves),
    // two proven-size waitcnt bindings; validate stamps; rare re-burst.
    i32x4 hvA[16], hvB[16];
    {
      const char* hb = (const char*)hcur;
      const unsigned E = (unsigned)(t + 1);
      while (true) {
#pragma unroll
        for (int kk = 0; kk < 16; kk++) {
          const char* ap = hb + (size_t)(((kk * 4 + q) * 64 + b0) << 5);
          asm volatile("global_load_dwordx4 %0, %1, off sc1"
                       : "=v"(hvA[kk]) : "v"(ap));
        }
#pragma unroll
        for (int kk = 0; kk < 16; kk++) {
          const char* ap = hb + (size_t)(((kk * 4 + q) * 64 + b0) << 5);
          asm volatile("global_load_dwordx4 %0, %1, off sc1"
                       : "=v"(hvB[kk]) : "v"(ap + 16));
        }
        asm volatile("s_waitcnt vmcnt(16)"
                     : "+v"(hvA[0]), "+v"(hvA[1]), "+v"(hvA[2]), "+v"(hvA[3]),
                       "+v"(hvA[4]), "+v"(hvA[5]), "+v"(hvA[6]), "+v"(hvA[7]),
                       "+v"(hvA[8]), "+v"(hvA[9]), "+v"(hvA[10]), "+v"(hvA[11]),
                       "+v"(hvA[12]), "+v"(hvA[13]), "+v"(hvA[14]), "+v"(hvA[15])
                     ::"memory");
        asm volatile("s_waitcnt vmcnt(0)"
                     : "+v"(hvB[0]), "+v"(hvB[1]), "+v"(hvB[2]), "+v"(hvB[3]),
                       "+v"(hvB[4]), "+v"(hvB[5]), "+v"(hvB[6]), "+v"(hvB[7]),
                       "+v"(hvB[8]), "+v"(hvB[9]), "+v"(hvB[10]), "+v"(hvB[11]),
                       "+v"(hvB[12]), "+v"(hvB[13]), "+v"(hvB[14]), "+v"(hvB[15])
                     ::"memory");
        if (t == 0) break;  // h0 certified by the init barrier
        unsigned bad = 0;
#pragma unroll
        for (int kk = 0; kk < 16; kk++) {
          bad |= ((unsigned)hvA[kk][0] ^ E) | ((unsigned)hvA[kk][2] ^ E) |
                 ((unsigned)hvB[kk][0] ^ E) | ((unsigned)hvB[kk][2] ^ E);
        }
        if (__all(bad == 0)) break;
        __builtin_amdgcn_s_sleep(1);  // tag outran data: brief backoff
      }
    }

    // h-projection: data pairs sit at dwords 1,3 of each half — no unpack
#pragma unroll
    for (int kk = 0; kk < 16; kk++) {
      i32x4 pk;
      pk[0] = hvA[kk][1];
      pk[1] = hvA[kk][3];
      pk[2] = hvB[kk][1];
      pk[3] = hvB[kk][3];
      bf16x8 a = __builtin_bit_cast(bf16x8, pk);
      aH0 = __builtin_amdgcn_mfma_f32_16x16x32_bf16(a, wh[0][kk], aH0, 0, 0, 0);
      aH1 = __builtin_amdgcn_mfma_f32_16x16x32_bf16(a, wh[1][kk], aH1, 0, 0, 0);
    }

    // epilogue: C/D layout col=lane&15, row=q*4+reg. Lane c<8 owns col wg*8+c.
    unsigned short* tr16 = (unsigned short*)&trans[wave][0][0];
    const unsigned stampv = (unsigned)(t + 2);
#pragma unroll
    for (int r = 0; r < 4; r++) {
      float xz = __shfl_xor(aX0[r], 8, 64);
      float hz = __shfl_xor(aH0[r], 8, 64);
      float rr = sigm(aX0[r] + bri + aH0[r] + brh);
      float zz = sigm(xz + bzi + hz + bzh);
      float nn = tanh_f(aX1[r] + bni + rr * (aH1[r] + bnh));
      float hv2 = (1.0f - zz) * nn + zz * hold[r];
      hold[r] = hv2;
      int row = q * 4 + r;
      if (c < 8)  // data ushort: chunk=(c>>1), dword 1 of chunk, half (c&1)
        tr16[row * 16 + (c >> 1) * 4 + 2 + (c & 1)] =
            (unsigned short)f2b(hv2);
      if (c < 4)  // stamp dwords 0,2,4,6 of the 32B row
        trans[wave][row][c * 2] = stampv;
    }

    if (t < NT - 1) {
      // per-wave LDS transpose -> 2 coalesced 16B sc1 stores, NO ack;
      // tag follows immediately (consumers validate stamps).
      asm volatile("s_waitcnt lgkmcnt(0)" ::: "memory");
      if (lane < 16) {
        int b = wave * 16 + lane;
        const i32x4* tp = (const i32x4*)&trans[wave][lane][0];
        i32x4 v0 = tp[0], v1 = tp[1];
        char* dst = (char*)hnext + (size_t)((wg * 64 + b) << 5);
        asm volatile("global_store_dwordx4 %0, %1, off sc1"
                     :: "v"(dst), "v"(v0) : "memory");
        asm volatile("global_store_dwordx4 %0, %1, off sc1"
                     :: "v"(dst + 16), "v"(v1) : "memory");
      }
      if (lane == 0)
        __hip_atomic_store(&mytags[wg], t + 2, __ATOMIC_RELAXED,
                           __HIP_MEMORY_SCOPE_AGENT);
    }
  }

  // final h (fp32 master copy) -> d_out
  if (c < 8) {
#pragma unroll
    for (int r = 0; r < 4; r++) {
      int b = wave * 16 + q * 4 + r;
      out[(size_t)b * NH + wg * 8 + c] = hold[r];
    }
  }
}

extern "C" void kernel_launch(void* const* d_in, const int* in_sizes, int n_in,
                              void* d_out, int out_size, void* d_ws, size_t ws_size,
                              hipStream_t stream) {
  const float* x   = (const float*)d_in[0];
  const float* Wih = (const float*)d_in[1];
  const float* Whh = (const float*)d_in[2];
  const float* bih = (const float*)d_in[3];
  const float* bhh = (const float*)d_in[4];
  float* out = (float*)d_out;
  hipLaunchKernelGGL(gru_persistent, dim3(NB), dim3(256), 0, stream,
                     x, Wih, Whh, bih, bhh, out, (unsigned char*)d_ws);
}